// Round 4
// baseline (719.926 us; speedup 1.0000x reference)
//
#include <hip/hip_runtime.h>

// UnstructuredNetwork via fp16 MFMA (v_mfma_f32_32x32x16_f16), fp32 accumulate.
// R4: LDS-free main loop. Activation redistribution (C-layout -> B-fragment)
// done in-register: lane n <-> lane n+32 exchange via __shfl_xor(,32)
// (ds_bpermute) + cndmask. Packed fp32 residual (v_pk_*_f32). h residual
// stays fp32; h-feed packs RNE, t-feed packs RTZ (within-layer only).

#define HID 20
#define NLAYERS 50
#define NEG 0.01f

typedef _Float16 half8   __attribute__((ext_vector_type(8)));
typedef _Float16 half2v  __attribute__((ext_vector_type(2)));
typedef __fp16   fp16x2  __attribute__((ext_vector_type(2)));
typedef float    floatx16 __attribute__((ext_vector_type(16)));
typedef float    float2v __attribute__((ext_vector_type(2)));
typedef unsigned uint4v  __attribute__((ext_vector_type(4)));

__device__ __forceinline__ unsigned pack_rne(float a, float b) {
    half2v p;
    p[0] = (_Float16)a;   // v_cvt_f16_f32 (RNE)
    p[1] = (_Float16)b;
    return __builtin_bit_cast(unsigned, p);
}

// ---------------- prepass: build A-operand fragments -----------------------
// A[m][k] = W[k][m] (k<20), A[m][20] = b[m], 0 otherwise (rows m>=20, k>=21).
// Lane l holds m=l&31, k = 16*ks + 8*(l>>5) + j (j=0..7).
// ws layout: wf[((L*2 + mk)*2 + ks)*64 + lane] : half8
__global__ void build_wfrags(const float* __restrict__ W1, const float* __restrict__ b1,
                             const float* __restrict__ W2, const float* __restrict__ b2,
                             half8* __restrict__ wf)
{
    const int L = blockIdx.x;
    const int l = threadIdx.x;           // 0..63
    const int m = l & 31, hh = l >> 5;
    const float* Ws[2] = { W1 + L * HID * HID, W2 + L * HID * HID };
    const float* bs[2] = { b1 + L * HID,       b2 + L * HID };
#pragma unroll
    for (int mk = 0; mk < 2; ++mk) {
#pragma unroll
        for (int ks = 0; ks < 2; ++ks) {
            half8 frag;
#pragma unroll
            for (int j = 0; j < 8; ++j) {
                int k = ks * 16 + hh * 8 + j;
                float v = 0.0f;
                if (m < HID) {
                    if (k < HID) v = Ws[mk][k * HID + m];
                    else if (k == HID) v = bs[mk][m];
                }
                frag[j] = (_Float16)v;
            }
            wf[((L * 2 + mk) * 2 + ks) * 64 + l] = frag;
        }
    }
}

// Build B-operand quads from 6 packed f16x2 regs (pair i = rows
// {0,2,8,10,16,18}[i] + 4*hh, +1). kstep1 needs the cross-half exchange;
// kstep2 is self + consts (hh=1's p4/p5 are genuine zeros; its k24-31
// columns multiply zero A-weights).
__device__ __forceinline__ void build_frags(const unsigned p[6], int hh,
                                            unsigned c10, half8* b0, half8* b1) {
    const unsigned s0 = (unsigned)__shfl_xor((int)p[0], 32, 64);
    const unsigned s1 = (unsigned)__shfl_xor((int)p[1], 32, 64);
    const unsigned s2 = (unsigned)__shfl_xor((int)p[2], 32, 64);
    const unsigned s3 = (unsigned)__shfl_xor((int)p[3], 32, 64);
    uint4v q0, q1;
    q0[0] = hh ? s2   : p[0];   // k {0-3}+8hh
    q0[1] = hh ? s3   : p[1];
    q0[2] = hh ? p[2] : s0;     // k {4-7}+8hh
    q0[3] = hh ? p[3] : s1;
    q1[0] = p[4];               // k16-17 (rows 16-17) / junk-zeros for hh=1
    q1[1] = p[5];               // k18-19
    q1[2] = c10;                // k20 = 1.0 (bias), k21 = 0
    q1[3] = 0u;                 // k22-23 = 0
    *b0 = __builtin_bit_cast(half8, q0);
    *b1 = __builtin_bit_cast(half8, q1);
}

// ---------------- main kernel (no LDS) -------------------------------------
__global__ __launch_bounds__(256, 4) void unet_mfma(
    const float* __restrict__ x,
    const float* __restrict__ lift_w,
    const float* __restrict__ lift_b,
    const float* __restrict__ dts,
    const float* __restrict__ proj_w,
    const float* __restrict__ proj_b,
    const half8* __restrict__ wf,
    float* __restrict__ out, int Bn)
{
    const int tid = threadIdx.x;
    const int wv  = tid >> 6;
    const int l   = tid & 63;
    const int n   = l & 31;
    const int hh  = l >> 5;

    const int g  = blockIdx.x * 128 + wv * 32 + n;
    const int gi = g < Bn ? g : Bn - 1;

    const float x0 = x[3 * gi + 0];
    const float x1 = x[3 * gi + 1];
    const float x2 = x[3 * gi + 2];

    // lift -> h2 (fp32 pairs, C-layout): pair i covers rows base(i)+4hh, +1
    float2v h2[6];
#pragma unroll
    for (int i = 0; i < 6; ++i) {
        const int r0   = 2 * i;
        const int row0 = (r0 & 3) + 8 * (r0 >> 2) + 4 * hh;
#pragma unroll
        for (int e = 0; e < 2; ++e) {
            const int row = row0 + e;
            if (row < HID) {
                float a = lift_b[row];
                a = fmaf(x0, lift_w[0 * HID + row], a);
                a = fmaf(x1, lift_w[1 * HID + row], a);
                a = fmaf(x2, lift_w[2 * HID + row], a);
                h2[i][e] = a;
            } else {
                h2[i][e] = 0.0f;
            }
        }
    }

    const unsigned C10 = 0x00003C00u;   // f16 (1.0, 0.0)
    const fp16x2  negs = {(__fp16)NEG, (__fp16)NEG};
    const float2v negf = {NEG, NEG};

    floatx16 zf;
#pragma unroll
    for (int i = 0; i < 16; ++i) zf[i] = 0.0f;

    // initial h -> B-fragments (RNE packs)
    half8 bh0, bh1;
    {
        unsigned p[6];
#pragma unroll
        for (int i = 0; i < 6; ++i) p[i] = pack_rne(h2[i][0], h2[i][1]);
        build_frags(p, hh, C10, &bh0, &bh1);
    }

    const half8* __restrict__ wp = wf + l;   // marches 256 half8 per layer

    for (int L = 0; L < NLAYERS; ++L) {
        const half8 a10 = wp[0];
        const half8 a11 = wp[64];
        const half8 a20 = wp[128];
        const half8 a21 = wp[192];
        wp += 256;
        const float dt = dts[L];
        const float2v dt2 = {dt, dt};

        // matmul1: t = W1^T(+b1) @ h
        floatx16 acc = __builtin_amdgcn_mfma_f32_32x32x16_f16(a10, bh0, zf, 0, 0, 0);
        acc = __builtin_amdgcn_mfma_f32_32x32x16_f16(a11, bh1, acc, 0, 0, 0);

        // t-feed: pkrtz + packed-f16 leaky (within-layer; RTZ ok)
        unsigned tp[6];
#pragma unroll
        for (int i = 0; i < 6; ++i) {
            fp16x2 z  = __builtin_amdgcn_cvt_pkrtz(acc[2 * i], acc[2 * i + 1]);
            fp16x2 t2 = __builtin_elementwise_max(z, z * negs);
            tp[i] = __builtin_bit_cast(unsigned, t2);
        }
        half8 bt0, bt1;
        build_frags(tp, hh, C10, &bt0, &bt1);

        // matmul2: u = W2^T(+b2) @ t
        floatx16 acc2 = __builtin_amdgcn_mfma_f32_32x32x16_f16(a20, bt0, zf, 0, 0, 0);
        acc2 = __builtin_amdgcn_mfma_f32_32x32x16_f16(a21, bt1, acc2, 0, 0, 0);

        // residual update, packed fp32: h += dt * max(u, 0.01u)
        unsigned p[6];
#pragma unroll
        for (int i = 0; i < 6; ++i) {
            float2v z  = {acc2[2 * i], acc2[2 * i + 1]};
            float2v lz = __builtin_elementwise_max(z, z * negf);
            h2[i] = __builtin_elementwise_fma(dt2, lz, h2[i]);
            p[i] = pack_rne(h2[i][0], h2[i][1]);   // RNE: residual stream
        }
        build_frags(p, hh, C10, &bh0, &bh1);
    }

    // projection; lanes l and l^32 hold complementary rows
    float po0 = 0.f, po1 = 0.f, po2 = 0.f;
#pragma unroll
    for (int i = 0; i < 6; ++i) {
#pragma unroll
        for (int e = 0; e < 2; ++e) {
            const int r0  = 2 * i;
            const int row = (r0 & 3) + 8 * (r0 >> 2) + 4 * hh + e;
            const float hv = (row < HID) ? h2[i][e] : 0.0f;
            const int rowc = (row < HID) ? row : 0;
            po0 = fmaf(hv, proj_w[rowc * 3 + 0], po0);
            po1 = fmaf(hv, proj_w[rowc * 3 + 1], po1);
            po2 = fmaf(hv, proj_w[rowc * 3 + 2], po2);
        }
    }
    po0 += __shfl_xor(po0, 32, 64);
    po1 += __shfl_xor(po1, 32, 64);
    po2 += __shfl_xor(po2, 32, 64);
    if (hh == 0 && g < Bn) {
        out[3 * g + 0] = po0 + proj_b[0];
        out[3 * g + 1] = po1 + proj_b[1];
        out[3 * g + 2] = po2 + proj_b[2];
    }
}

extern "C" void kernel_launch(void* const* d_in, const int* in_sizes, int n_in,
                              void* d_out, int out_size, void* d_ws, size_t ws_size,
                              hipStream_t stream) {
    const float* x      = (const float*)d_in[0];
    const float* lift_w = (const float*)d_in[1];
    const float* lift_b = (const float*)d_in[2];
    const float* W1     = (const float*)d_in[3];
    const float* b1     = (const float*)d_in[4];
    const float* W2     = (const float*)d_in[5];
    const float* b2     = (const float*)d_in[6];
    const float* dts    = (const float*)d_in[7];
    const float* proj_w = (const float*)d_in[8];
    const float* proj_b = (const float*)d_in[9];
    float* out = (float*)d_out;

    const int B = in_sizes[0] / 3;
    half8* wf = (half8*)d_ws;   // NLAYERS*4*64*16 B = 200 KiB

    build_wfrags<<<NLAYERS, 64, 0, stream>>>(W1, b1, W2, b2, wf);

    const int blocks = (B + 127) / 128;   // 128 samples/block (4 waves x 32)
    unet_mfma<<<blocks, 256, 0, stream>>>(
        x, lift_w, lift_b, dts, proj_w, proj_b, wf, out, B);
}

// Round 5
// 632.649 us; speedup vs baseline: 1.1380x; 1.1380x over previous
//
#include <hip/hip_runtime.h>

// UnstructuredNetwork via fp16 MFMA (v_mfma_f32_32x32x16_f16), fp32 accumulate.
// R5: h residual kept in PACKED F16 registers (6 x fp16x2) — h pairs are the
// B-fragment payload directly (no per-layer pack_rne). Residual update via
// v_pk_fma_f16 (RNE); only the u->f16 conversion is RTZ (pkrtz). LDS-free:
// C-layout -> B-fragment redistribution via __shfl_xor(,32) + cndmask.
// MFMA floor for this tiling = 128 cyc/SIMD per wave-layer (~163 us).

#define HID 20
#define NLAYERS 50
#define NEG 0.01f

typedef _Float16 half8   __attribute__((ext_vector_type(8)));
typedef _Float16 half2v  __attribute__((ext_vector_type(2)));
typedef __fp16   fp16x2  __attribute__((ext_vector_type(2)));
typedef float    floatx16 __attribute__((ext_vector_type(16)));
typedef unsigned uint4v  __attribute__((ext_vector_type(4)));

__device__ __forceinline__ unsigned pack_rne(float a, float b) {
    half2v p;
    p[0] = (_Float16)a;   // v_cvt_f16_f32 (RNE)
    p[1] = (_Float16)b;
    return __builtin_bit_cast(unsigned, p);
}

// ---------------- prepass: build A-operand fragments -----------------------
// A[m][k] = W[k][m] (k<20), A[m][20] = b[m], 0 otherwise (rows m>=20, k>=21).
// Lane l holds m=l&31, k = 16*ks + 8*(l>>5) + j (j=0..7).
// ws layout: wf[((L*2 + mk)*2 + ks)*64 + lane] : half8
__global__ void build_wfrags(const float* __restrict__ W1, const float* __restrict__ b1,
                             const float* __restrict__ W2, const float* __restrict__ b2,
                             half8* __restrict__ wf)
{
    const int L = blockIdx.x;
    const int l = threadIdx.x;           // 0..63
    const int m = l & 31, hh = l >> 5;
    const float* Ws[2] = { W1 + L * HID * HID, W2 + L * HID * HID };
    const float* bs[2] = { b1 + L * HID,       b2 + L * HID };
#pragma unroll
    for (int mk = 0; mk < 2; ++mk) {
#pragma unroll
        for (int ks = 0; ks < 2; ++ks) {
            half8 frag;
#pragma unroll
            for (int j = 0; j < 8; ++j) {
                int k = ks * 16 + hh * 8 + j;
                float v = 0.0f;
                if (m < HID) {
                    if (k < HID) v = Ws[mk][k * HID + m];
                    else if (k == HID) v = bs[mk][m];
                }
                frag[j] = (_Float16)v;
            }
            wf[((L * 2 + mk) * 2 + ks) * 64 + l] = frag;
        }
    }
}

// Build B-operand quads from 6 packed f16x2 regs (pair i of lane (n,hh) holds
// rows: i<2 -> 2i+4hh..; i<4 -> 8+2(i-2)+4hh..; else 16+2(i-4)+4hh..).
// kstep1 needs the cross-half exchange; kstep2 is self + consts (hh=1's
// pairs 4,5 are exact zeros; its k24-31 columns multiply zero A-weights).
__device__ __forceinline__ void build_frags(const unsigned p[6], int hh,
                                            unsigned c10, half8* b0, half8* b1) {
    const unsigned s0 = (unsigned)__shfl_xor((int)p[0], 32, 64);
    const unsigned s1 = (unsigned)__shfl_xor((int)p[1], 32, 64);
    const unsigned s2 = (unsigned)__shfl_xor((int)p[2], 32, 64);
    const unsigned s3 = (unsigned)__shfl_xor((int)p[3], 32, 64);
    uint4v q0, q1;
    q0[0] = hh ? s2   : p[0];   // k {0-3}+8hh
    q0[1] = hh ? s3   : p[1];
    q0[2] = hh ? p[2] : s0;     // k {4-7}+8hh
    q0[3] = hh ? p[3] : s1;
    q1[0] = p[4];               // k16-17 (rows 16-17); exact zeros for hh=1
    q1[1] = p[5];               // k18-19
    q1[2] = c10;                // k20 = 1.0 (bias), k21 = 0
    q1[3] = 0u;                 // k22-23 = 0
    *b0 = __builtin_bit_cast(half8, q0);
    *b1 = __builtin_bit_cast(half8, q1);
}

// ---------------- main kernel (no LDS, f16 residual) -----------------------
__global__ __launch_bounds__(256, 4) void unet_mfma(
    const float* __restrict__ x,
    const float* __restrict__ lift_w,
    const float* __restrict__ lift_b,
    const float* __restrict__ dts,
    const float* __restrict__ proj_w,
    const float* __restrict__ proj_b,
    const half8* __restrict__ wf,
    float* __restrict__ out, int Bn)
{
    const int tid = threadIdx.x;
    const int wv  = tid >> 6;
    const int l   = tid & 63;
    const int n   = l & 31;
    const int hh  = l >> 5;

    const int g  = blockIdx.x * 128 + wv * 32 + n;
    const int gi = g < Bn ? g : Bn - 1;

    const float x0 = x[3 * gi + 0];
    const float x1 = x[3 * gi + 1];
    const float x2 = x[3 * gi + 2];

    // lift in fp32, then one-time RNE pack into the f16 residual pairs.
    // Pair i of this lane covers rows row0(i)+4hh, +1 (rows >= HID -> 0).
    unsigned hp[6];
#pragma unroll
    for (int i = 0; i < 6; ++i) {
        const int r0   = 2 * i;
        const int row0 = (r0 & 3) + 8 * (r0 >> 2) + 4 * hh;
        float v[2];
#pragma unroll
        for (int e = 0; e < 2; ++e) {
            const int row = row0 + e;
            if (row < HID) {
                float a = lift_b[row];
                a = fmaf(x0, lift_w[0 * HID + row], a);
                a = fmaf(x1, lift_w[1 * HID + row], a);
                a = fmaf(x2, lift_w[2 * HID + row], a);
                v[e] = a;
            } else {
                v[e] = 0.0f;
            }
        }
        hp[i] = pack_rne(v[0], v[1]);
    }
    fp16x2 h[6];
#pragma unroll
    for (int i = 0; i < 6; ++i) h[i] = __builtin_bit_cast(fp16x2, hp[i]);

    const unsigned C10 = 0x00003C00u;   // f16 (1.0, 0.0)
    const fp16x2  negs = {(__fp16)NEG, (__fp16)NEG};

    floatx16 zf;
#pragma unroll
    for (int i = 0; i < 16; ++i) zf[i] = 0.0f;

    half8 bh0, bh1;
    build_frags(hp, hh, C10, &bh0, &bh1);

    const half8* __restrict__ wfl = wf + l;

    for (int L = 0; L < NLAYERS; ++L) {
        const half8 a10 = wfl[L * 256 + 0];
        const half8 a11 = wfl[L * 256 + 64];
        const half8 a20 = wfl[L * 256 + 128];
        const half8 a21 = wfl[L * 256 + 192];
        const float dtf = dts[L];
        const __fp16 dth = (__fp16)dtf;
        const fp16x2 dtp = {dth, dth};

        // matmul1: t = W1^T(+b1) @ h
        floatx16 acc = __builtin_amdgcn_mfma_f32_32x32x16_f16(a10, bh0, zf, 0, 0, 0);
        acc = __builtin_amdgcn_mfma_f32_32x32x16_f16(a11, bh1, acc, 0, 0, 0);

        // t-feed: pkrtz + packed-f16 leaky (within-layer; RTZ ok)
        unsigned tp[6];
#pragma unroll
        for (int i = 0; i < 6; ++i) {
            fp16x2 z  = __builtin_amdgcn_cvt_pkrtz(acc[2 * i], acc[2 * i + 1]);
            fp16x2 t2 = __builtin_elementwise_max(z, z * negs);
            tp[i] = __builtin_bit_cast(unsigned, t2);
        }
        half8 bt0, bt1;
        build_frags(tp, hh, C10, &bt0, &bt1);

        // matmul2: u = W2^T(+b2) @ t
        floatx16 acc2 = __builtin_amdgcn_mfma_f32_32x32x16_f16(a20, bt0, zf, 0, 0, 0);
        acc2 = __builtin_amdgcn_mfma_f32_32x32x16_f16(a21, bt1, acc2, 0, 0, 0);

        // residual in packed f16 (RNE fma): h += dt * max(u, 0.01u)
#pragma unroll
        for (int i = 0; i < 6; ++i) {
            fp16x2 z  = __builtin_amdgcn_cvt_pkrtz(acc2[2 * i], acc2[2 * i + 1]);
            fp16x2 lz = __builtin_elementwise_max(z, z * negs);
            h[i] = __builtin_elementwise_fma(dtp, lz, h[i]);
            hp[i] = __builtin_bit_cast(unsigned, h[i]);
        }
        build_frags(hp, hh, C10, &bh0, &bh1);
    }

    // projection; lanes l and l^32 hold complementary rows
    float po0 = 0.f, po1 = 0.f, po2 = 0.f;
#pragma unroll
    for (int i = 0; i < 6; ++i) {
#pragma unroll
        for (int e = 0; e < 2; ++e) {
            const int r0  = 2 * i;
            const int row = (r0 & 3) + 8 * (r0 >> 2) + 4 * hh + e;
            const float hv = (row < HID) ? (float)h[i][e] : 0.0f;
            const int rowc = (row < HID) ? row : 0;
            po0 = fmaf(hv, proj_w[rowc * 3 + 0], po0);
            po1 = fmaf(hv, proj_w[rowc * 3 + 1], po1);
            po2 = fmaf(hv, proj_w[rowc * 3 + 2], po2);
        }
    }
    po0 += __shfl_xor(po0, 32, 64);
    po1 += __shfl_xor(po1, 32, 64);
    po2 += __shfl_xor(po2, 32, 64);
    if (hh == 0 && g < Bn) {
        out[3 * g + 0] = po0 + proj_b[0];
        out[3 * g + 1] = po1 + proj_b[1];
        out[3 * g + 2] = po2 + proj_b[2];
    }
}

extern "C" void kernel_launch(void* const* d_in, const int* in_sizes, int n_in,
                              void* d_out, int out_size, void* d_ws, size_t ws_size,
                              hipStream_t stream) {
    const float* x      = (const float*)d_in[0];
    const float* lift_w = (const float*)d_in[1];
    const float* lift_b = (const float*)d_in[2];
    const float* W1     = (const float*)d_in[3];
    const float* b1     = (const float*)d_in[4];
    const float* W2     = (const float*)d_in[5];
    const float* b2     = (const float*)d_in[6];
    const float* dts    = (const float*)d_in[7];
    const float* proj_w = (const float*)d_in[8];
    const float* proj_b = (const float*)d_in[9];
    float* out = (float*)d_out;

    const int B = in_sizes[0] / 3;
    half8* wf = (half8*)d_ws;   // NLAYERS*4*64*16 B = 200 KiB

    build_wfrags<<<NLAYERS, 64, 0, stream>>>(W1, b1, W2, b2, wf);

    const int blocks = (B + 127) / 128;   // 128 samples/block (4 waves x 32)
    unet_mfma<<<blocks, 256, 0, stream>>>(
        x, lift_w, lift_b, dts, proj_w, proj_b, wf, out, B);
}

// Round 6
// 571.103 us; speedup vs baseline: 1.2606x; 1.1078x over previous
//
#include <hip/hip_runtime.h>

// UnstructuredNetwork via fp16 MFMA (v_mfma_f32_32x32x16_f16), fp32 accumulate.
// R6: weight-space permutation kills the C->B redistribution entirely.
//   C-layout row ownership: hh=0 holds rows {0-3,8-11,16-19}, hh=1 {4-7,12-15}.
//   B-fragment k ownership:  hh=0 supplies k{0-7,16-19},     hh=1 k{8-15}.
//   Map phi (involution, swaps 4-7<->8-11) applied to each W's INPUT index in
//   the prepass makes packed C pairs the B fragments verbatim:
//   q0={tp0..tp3}, q1={tp4,tp5,biasconst,0} -- no shfl, no cndmask, both halves.
// h residual in packed f16 regs; t-feed RTZ (within-layer), residual fma RNE.
// dt pre-packed to f16x2 in prepass (uniform s_load in main loop).

#define HID 20
#define NLAYERS 50
#define NEG 0.01f

typedef _Float16 half8   __attribute__((ext_vector_type(8)));
typedef _Float16 half2v  __attribute__((ext_vector_type(2)));
typedef __fp16   fp16x2  __attribute__((ext_vector_type(2)));
typedef float    floatx16 __attribute__((ext_vector_type(16)));
typedef unsigned uint4v  __attribute__((ext_vector_type(4)));

__device__ __forceinline__ unsigned pack_rne(float a, float b) {
    half2v p;
    p[0] = (_Float16)a;   // v_cvt_f16_f32 (RNE)
    p[1] = (_Float16)b;
    return __builtin_bit_cast(unsigned, p);
}

// position->k involution: swap 4-7 <-> 8-11, fix the rest
__device__ __forceinline__ int phi(int k) {
    if (k >= 4 && k < 8)  return k + 4;
    if (k >= 8 && k < 12) return k - 4;
    return k;
}

// ---------------- prepass: build A-operand fragments -----------------------
// A'[m][k] = W[phi(k)][m] (k<20), A'[m][20] = b[m], 0 otherwise.
// Lane l holds m=l&31, k = 16*ks + 8*(l>>5) + j (j=0..7).
// ws layout: wf[((L*2 + mk)*2 + ks)*64 + lane] : half8 ; then 50 packed dt f16x2.
__global__ void build_wfrags(const float* __restrict__ W1, const float* __restrict__ b1,
                             const float* __restrict__ W2, const float* __restrict__ b2,
                             const float* __restrict__ dts,
                             half8* __restrict__ wf)
{
    const int L = blockIdx.x;
    const int l = threadIdx.x;           // 0..63
    const int m = l & 31, hh = l >> 5;
    const float* Ws[2] = { W1 + L * HID * HID, W2 + L * HID * HID };
    const float* bs[2] = { b1 + L * HID,       b2 + L * HID };
#pragma unroll
    for (int mk = 0; mk < 2; ++mk) {
#pragma unroll
        for (int ks = 0; ks < 2; ++ks) {
            half8 frag;
#pragma unroll
            for (int j = 0; j < 8; ++j) {
                int k = ks * 16 + hh * 8 + j;
                float v = 0.0f;
                if (m < HID) {
                    if (k < HID) v = Ws[mk][phi(k) * HID + m];
                    else if (k == HID) v = bs[mk][m];
                }
                frag[j] = (_Float16)v;
            }
            wf[((L * 2 + mk) * 2 + ks) * 64 + l] = frag;
        }
    }
    if (l == 0) {
        unsigned* dtp = (unsigned*)(wf + NLAYERS * 256);
        const __fp16 d = (__fp16)dts[L];
        fp16x2 dp = {d, d};
        dtp[L] = __builtin_bit_cast(unsigned, dp);
    }
}

// ---------------- main kernel (no LDS, no shuffles, f16 residual) ----------
__global__ __launch_bounds__(256, 4) void unet_mfma(
    const float* __restrict__ x,
    const float* __restrict__ lift_w,
    const float* __restrict__ lift_b,
    const float* __restrict__ proj_w,
    const float* __restrict__ proj_b,
    const half8* __restrict__ wf,
    float* __restrict__ out, int Bn)
{
    const int tid = threadIdx.x;
    const int wv  = tid >> 6;
    const int l   = tid & 63;
    const int n   = l & 31;
    const int hh  = l >> 5;

    const int g  = blockIdx.x * 128 + wv * 32 + n;
    const int gi = g < Bn ? g : Bn - 1;

    const float x0 = x[3 * gi + 0];
    const float x1 = x[3 * gi + 1];
    const float x2 = x[3 * gi + 2];

    // lift in fp32, one-time RNE pack into f16 residual pairs.
    // Pair i covers C rows row0(i)+4hh, +1 (rows >= HID stay 0 forever).
    unsigned hp[6];
#pragma unroll
    for (int i = 0; i < 6; ++i) {
        const int r0   = 2 * i;
        const int row0 = (r0 & 3) + 8 * (r0 >> 2) + 4 * hh;
        float v[2];
#pragma unroll
        for (int e = 0; e < 2; ++e) {
            const int row = row0 + e;
            if (row < HID) {
                float a = lift_b[row];
                a = fmaf(x0, lift_w[0 * HID + row], a);
                a = fmaf(x1, lift_w[1 * HID + row], a);
                a = fmaf(x2, lift_w[2 * HID + row], a);
                v[e] = a;
            } else {
                v[e] = 0.0f;
            }
        }
        hp[i] = pack_rne(v[0], v[1]);
    }
    fp16x2 h[6];
#pragma unroll
    for (int i = 0; i < 6; ++i) h[i] = __builtin_bit_cast(fp16x2, hp[i]);

    const unsigned C10 = 0x00003C00u;   // f16 (1.0, 0.0): k20 bias mult, k21 = 0
    const fp16x2  negs = {(__fp16)NEG, (__fp16)NEG};

    floatx16 zf;
#pragma unroll
    for (int i = 0; i < 16; ++i) zf[i] = 0.0f;

    const unsigned* __restrict__ dtp = (const unsigned*)(wf + NLAYERS * 256);
    const half8* __restrict__ wp = wf + l;   // marches 256 half8 per layer

    // initial B fragments straight from packed h pairs
    half8 bh0 = __builtin_bit_cast(half8, (uint4v){hp[0], hp[1], hp[2], hp[3]});
    half8 bh1 = __builtin_bit_cast(half8, (uint4v){hp[4], hp[5], C10, 0u});

    for (int L = 0; L < NLAYERS; ++L) {
        const half8 a10 = wp[0];
        const half8 a11 = wp[64];
        const half8 a20 = wp[128];
        const half8 a21 = wp[192];
        wp += 256;
        const fp16x2 dt2 = __builtin_bit_cast(fp16x2, dtp[L]);

        // matmul1: t = A1' @ h  (C = hoisted zeros)
        floatx16 acc = __builtin_amdgcn_mfma_f32_32x32x16_f16(a10, bh0, zf, 0, 0, 0);
        acc = __builtin_amdgcn_mfma_f32_32x32x16_f16(a11, bh1, acc, 0, 0, 0);

        // t-feed: pkrtz + packed-f16 leaky; pairs ARE the next B fragments
        unsigned tp[6];
#pragma unroll
        for (int i = 0; i < 6; ++i) {
            fp16x2 z  = __builtin_amdgcn_cvt_pkrtz(acc[2 * i], acc[2 * i + 1]);
            fp16x2 t2 = __builtin_elementwise_max(z, z * negs);
            tp[i] = __builtin_bit_cast(unsigned, t2);
        }
        const half8 bt0 = __builtin_bit_cast(half8, (uint4v){tp[0], tp[1], tp[2], tp[3]});
        const half8 bt1 = __builtin_bit_cast(half8, (uint4v){tp[4], tp[5], C10, 0u});

        // matmul2: u = A2' @ t
        floatx16 acc2 = __builtin_amdgcn_mfma_f32_32x32x16_f16(a20, bt0, zf, 0, 0, 0);
        acc2 = __builtin_amdgcn_mfma_f32_32x32x16_f16(a21, bt1, acc2, 0, 0, 0);

        // residual in packed f16 (RNE fma): h += dt * max(u, 0.01u)
#pragma unroll
        for (int i = 0; i < 6; ++i) {
            fp16x2 z  = __builtin_amdgcn_cvt_pkrtz(acc2[2 * i], acc2[2 * i + 1]);
            fp16x2 lz = __builtin_elementwise_max(z, z * negs);
            h[i] = __builtin_elementwise_fma(dt2, lz, h[i]);
            hp[i] = __builtin_bit_cast(unsigned, h[i]);
        }
        bh0 = __builtin_bit_cast(half8, (uint4v){hp[0], hp[1], hp[2], hp[3]});
        bh1 = __builtin_bit_cast(half8, (uint4v){hp[4], hp[5], C10, 0u});
    }

    // projection; lanes l and l^32 hold complementary rows
    float po0 = 0.f, po1 = 0.f, po2 = 0.f;
#pragma unroll
    for (int i = 0; i < 6; ++i) {
#pragma unroll
        for (int e = 0; e < 2; ++e) {
            const int r0  = 2 * i;
            const int row = (r0 & 3) + 8 * (r0 >> 2) + 4 * hh + e;
            const float hv = (row < HID) ? (float)h[i][e] : 0.0f;
            const int rowc = (row < HID) ? row : 0;
            po0 = fmaf(hv, proj_w[rowc * 3 + 0], po0);
            po1 = fmaf(hv, proj_w[rowc * 3 + 1], po1);
            po2 = fmaf(hv, proj_w[rowc * 3 + 2], po2);
        }
    }
    po0 += __shfl_xor(po0, 32, 64);
    po1 += __shfl_xor(po1, 32, 64);
    po2 += __shfl_xor(po2, 32, 64);
    if (hh == 0 && g < Bn) {
        out[3 * g + 0] = po0 + proj_b[0];
        out[3 * g + 1] = po1 + proj_b[1];
        out[3 * g + 2] = po2 + proj_b[2];
    }
}

extern "C" void kernel_launch(void* const* d_in, const int* in_sizes, int n_in,
                              void* d_out, int out_size, void* d_ws, size_t ws_size,
                              hipStream_t stream) {
    const float* x      = (const float*)d_in[0];
    const float* lift_w = (const float*)d_in[1];
    const float* lift_b = (const float*)d_in[2];
    const float* W1     = (const float*)d_in[3];
    const float* b1     = (const float*)d_in[4];
    const float* W2     = (const float*)d_in[5];
    const float* b2     = (const float*)d_in[6];
    const float* dts    = (const float*)d_in[7];
    const float* proj_w = (const float*)d_in[8];
    const float* proj_b = (const float*)d_in[9];
    float* out = (float*)d_out;

    const int B = in_sizes[0] / 3;
    half8* wf = (half8*)d_ws;   // NLAYERS*4*64*16 B = 200 KiB + 200 B dt table

    build_wfrags<<<NLAYERS, 64, 0, stream>>>(W1, b1, W2, b2, dts, wf);

    const int blocks = (B + 127) / 128;   // 128 samples/block (4 waves x 32)
    unet_mfma<<<blocks, 256, 0, stream>>>(
        x, lift_w, lift_b, proj_w, proj_b, wf, out, B);
}

// Round 7
// 474.924 us; speedup vs baseline: 1.5159x; 1.2025x over previous
//
#include <hip/hip_runtime.h>

// UnstructuredNetwork via fp16 MFMA (v_mfma_f32_32x32x16_f16), fp32 accumulate.
// R7: 64 samples/wave (two B-groups sharing A fragments) + explicit
// double-buffered weight prefetch (hides L2-miss latency: the x/out stream
// evicts the 200 KiB weight set, so per-layer fragment loads were L3-latency
// and unpipelined at VGPR=36 — R6's ~140 cyc/wave-layer stall).
// R6's phi-permutation keeps C pairs == B fragments (no shfl/cndmask).
// h residual in packed f16; t-feed RTZ (within-layer), residual fma RNE.

#define HID 20
#define NLAYERS 50
#define NEG 0.01f

typedef _Float16 half8   __attribute__((ext_vector_type(8)));
typedef _Float16 half2v  __attribute__((ext_vector_type(2)));
typedef __fp16   fp16x2  __attribute__((ext_vector_type(2)));
typedef float    floatx16 __attribute__((ext_vector_type(16)));
typedef unsigned uint4v  __attribute__((ext_vector_type(4)));

__device__ __forceinline__ unsigned pack_rne(float a, float b) {
    half2v p;
    p[0] = (_Float16)a;   // v_cvt_f16_f32 (RNE)
    p[1] = (_Float16)b;
    return __builtin_bit_cast(unsigned, p);
}

// position->k involution: swap 4-7 <-> 8-11, fix the rest
__device__ __forceinline__ int phi(int k) {
    if (k >= 4 && k < 8)  return k + 4;
    if (k >= 8 && k < 12) return k - 4;
    return k;
}

// ---------------- prepass: build A-operand fragments -----------------------
// A'[m][k] = W[phi(k)][m] (k<20), A'[m][20] = b[m], 0 otherwise.
// Lane l holds m=l&31, k = 16*ks + 8*(l>>5) + j (j=0..7).
// ws layout: wf[((L*2 + mk)*2 + ks)*64 + lane] : half8 ; then 50 packed dt f16x2.
__global__ void build_wfrags(const float* __restrict__ W1, const float* __restrict__ b1,
                             const float* __restrict__ W2, const float* __restrict__ b2,
                             const float* __restrict__ dts,
                             half8* __restrict__ wf)
{
    const int L = blockIdx.x;
    const int l = threadIdx.x;           // 0..63
    const int m = l & 31, hh = l >> 5;
    const float* Ws[2] = { W1 + L * HID * HID, W2 + L * HID * HID };
    const float* bs[2] = { b1 + L * HID,       b2 + L * HID };
#pragma unroll
    for (int mk = 0; mk < 2; ++mk) {
#pragma unroll
        for (int ks = 0; ks < 2; ++ks) {
            half8 frag;
#pragma unroll
            for (int j = 0; j < 8; ++j) {
                int k = ks * 16 + hh * 8 + j;
                float v = 0.0f;
                if (m < HID) {
                    if (k < HID) v = Ws[mk][phi(k) * HID + m];
                    else if (k == HID) v = bs[mk][m];
                }
                frag[j] = (_Float16)v;
            }
            wf[((L * 2 + mk) * 2 + ks) * 64 + l] = frag;
        }
    }
    if (l == 0) {
        unsigned* dtp = (unsigned*)(wf + NLAYERS * 256);
        const __fp16 d = (__fp16)dts[L];
        fp16x2 dp = {d, d};
        dtp[L] = __builtin_bit_cast(unsigned, dp);
    }
}

// ---------------- main kernel --------------------------------------------
__global__ __launch_bounds__(256, 4) void unet_mfma(
    const float* __restrict__ x,
    const float* __restrict__ lift_w,
    const float* __restrict__ lift_b,
    const float* __restrict__ proj_w,
    const float* __restrict__ proj_b,
    const half8* __restrict__ wf,
    float* __restrict__ out, int Bn)
{
    const int tid = threadIdx.x;
    const int wv  = tid >> 6;
    const int l   = tid & 63;
    const int n   = l & 31;
    const int hh  = l >> 5;

    const int gA  = blockIdx.x * 256 + wv * 64 + n;   // group A sample
    const int gB  = gA + 32;                          // group B sample
    const int giA = gA < Bn ? gA : Bn - 1;
    const int giB = gB < Bn ? gB : Bn - 1;

    const unsigned C10 = 0x00003C00u;   // f16 (1.0, 0.0): k20 bias, k21 = 0
    const fp16x2  negs = {(__fp16)NEG, (__fp16)NEG};

    // ---- lift both groups (fp32 -> RNE f16 pairs, C-layout rows) ----
    fp16x2 hA[6], hB[6];
    unsigned hpA[6], hpB[6];
    {
        const float xA0 = x[3 * giA + 0], xA1 = x[3 * giA + 1], xA2 = x[3 * giA + 2];
        const float xB0 = x[3 * giB + 0], xB1 = x[3 * giB + 1], xB2 = x[3 * giB + 2];
#pragma unroll
        for (int i = 0; i < 6; ++i) {
            const int r0   = 2 * i;
            const int row0 = (r0 & 3) + 8 * (r0 >> 2) + 4 * hh;
            float vA[2], vB[2];
#pragma unroll
            for (int e = 0; e < 2; ++e) {
                const int row = row0 + e;
                if (row < HID) {
                    const float w0 = lift_w[0 * HID + row];
                    const float w1 = lift_w[1 * HID + row];
                    const float w2 = lift_w[2 * HID + row];
                    const float b  = lift_b[row];
                    vA[e] = fmaf(xA2, w2, fmaf(xA1, w1, fmaf(xA0, w0, b)));
                    vB[e] = fmaf(xB2, w2, fmaf(xB1, w1, fmaf(xB0, w0, b)));
                } else { vA[e] = 0.0f; vB[e] = 0.0f; }
            }
            hpA[i] = pack_rne(vA[0], vA[1]);
            hpB[i] = pack_rne(vB[0], vB[1]);
        }
    }
#pragma unroll
    for (int i = 0; i < 6; ++i) {
        hA[i] = __builtin_bit_cast(fp16x2, hpA[i]);
        hB[i] = __builtin_bit_cast(fp16x2, hpB[i]);
    }

    floatx16 zf;
#pragma unroll
    for (int i = 0; i < 16; ++i) zf[i] = 0.0f;

    const unsigned* __restrict__ dtp = (const unsigned*)(wf + NLAYERS * 256);

    half8 bhA0 = __builtin_bit_cast(half8, (uint4v){hpA[0], hpA[1], hpA[2], hpA[3]});
    half8 bhA1 = __builtin_bit_cast(half8, (uint4v){hpA[4], hpA[5], C10, 0u});
    half8 bhB0 = __builtin_bit_cast(half8, (uint4v){hpB[0], hpB[1], hpB[2], hpB[3]});
    half8 bhB1 = __builtin_bit_cast(half8, (uint4v){hpB[4], hpB[5], C10, 0u});

    // ---- double-buffered weight prefetch ----
    const half8* __restrict__ wl = wf + l;
    half8 c0 = wl[0], c1 = wl[64], c2 = wl[128], c3 = wl[192];

    for (int L = 0; L < NLAYERS; ++L) {
        // prefetch layer L+1 (last iter refetches layer 49; in-bounds, unused)
        const int Ln = (L + 1 < NLAYERS) ? (L + 1) : (NLAYERS - 1);
        const half8* __restrict__ wn = wf + l + Ln * 256;
        const half8 p0 = wn[0], p1 = wn[64], p2 = wn[128], p3 = wn[192];

        const fp16x2 dt2 = __builtin_bit_cast(fp16x2, dtp[L]);

        // matmul1 both groups (independent MFMA stream)
        floatx16 accA = __builtin_amdgcn_mfma_f32_32x32x16_f16(c0, bhA0, zf, 0, 0, 0);
        floatx16 accB = __builtin_amdgcn_mfma_f32_32x32x16_f16(c0, bhB0, zf, 0, 0, 0);
        accA = __builtin_amdgcn_mfma_f32_32x32x16_f16(c1, bhA1, accA, 0, 0, 0);
        accB = __builtin_amdgcn_mfma_f32_32x32x16_f16(c1, bhB1, accB, 0, 0, 0);

        // t-feed: pkrtz + packed-f16 leaky; pairs ARE the next B fragments
        unsigned tpA[6], tpB[6];
#pragma unroll
        for (int i = 0; i < 6; ++i) {
            fp16x2 zA = __builtin_amdgcn_cvt_pkrtz(accA[2 * i], accA[2 * i + 1]);
            fp16x2 zB = __builtin_amdgcn_cvt_pkrtz(accB[2 * i], accB[2 * i + 1]);
            fp16x2 tA = __builtin_elementwise_max(zA, zA * negs);
            fp16x2 tB = __builtin_elementwise_max(zB, zB * negs);
            tpA[i] = __builtin_bit_cast(unsigned, tA);
            tpB[i] = __builtin_bit_cast(unsigned, tB);
        }
        const half8 btA0 = __builtin_bit_cast(half8, (uint4v){tpA[0], tpA[1], tpA[2], tpA[3]});
        const half8 btA1 = __builtin_bit_cast(half8, (uint4v){tpA[4], tpA[5], C10, 0u});
        const half8 btB0 = __builtin_bit_cast(half8, (uint4v){tpB[0], tpB[1], tpB[2], tpB[3]});
        const half8 btB1 = __builtin_bit_cast(half8, (uint4v){tpB[4], tpB[5], C10, 0u});

        // matmul2 both groups
        floatx16 acc2A = __builtin_amdgcn_mfma_f32_32x32x16_f16(c2, btA0, zf, 0, 0, 0);
        floatx16 acc2B = __builtin_amdgcn_mfma_f32_32x32x16_f16(c2, btB0, zf, 0, 0, 0);
        acc2A = __builtin_amdgcn_mfma_f32_32x32x16_f16(c3, btA1, acc2A, 0, 0, 0);
        acc2B = __builtin_amdgcn_mfma_f32_32x32x16_f16(c3, btB1, acc2B, 0, 0, 0);

        // residual in packed f16 (RNE fma): h += dt * max(u, 0.01u)
#pragma unroll
        for (int i = 0; i < 6; ++i) {
            fp16x2 zA = __builtin_amdgcn_cvt_pkrtz(acc2A[2 * i], acc2A[2 * i + 1]);
            fp16x2 zB = __builtin_amdgcn_cvt_pkrtz(acc2B[2 * i], acc2B[2 * i + 1]);
            fp16x2 lA = __builtin_elementwise_max(zA, zA * negs);
            fp16x2 lB = __builtin_elementwise_max(zB, zB * negs);
            hA[i] = __builtin_elementwise_fma(dt2, lA, hA[i]);
            hB[i] = __builtin_elementwise_fma(dt2, lB, hB[i]);
            hpA[i] = __builtin_bit_cast(unsigned, hA[i]);
            hpB[i] = __builtin_bit_cast(unsigned, hB[i]);
        }
        bhA0 = __builtin_bit_cast(half8, (uint4v){hpA[0], hpA[1], hpA[2], hpA[3]});
        bhA1 = __builtin_bit_cast(half8, (uint4v){hpA[4], hpA[5], C10, 0u});
        bhB0 = __builtin_bit_cast(half8, (uint4v){hpB[0], hpB[1], hpB[2], hpB[3]});
        bhB1 = __builtin_bit_cast(half8, (uint4v){hpB[4], hpB[5], C10, 0u});

        // rotate weight buffers
        c0 = p0; c1 = p1; c2 = p2; c3 = p3;
    }

    // ---- projection, both groups ----
    float aO0 = 0.f, aO1 = 0.f, aO2 = 0.f, bO0 = 0.f, bO1 = 0.f, bO2 = 0.f;
#pragma unroll
    for (int i = 0; i < 6; ++i) {
#pragma unroll
        for (int e = 0; e < 2; ++e) {
            const int r0  = 2 * i;
            const int row = (r0 & 3) + 8 * (r0 >> 2) + 4 * hh + e;
            if (row < HID) {
                const float w0 = proj_w[row * 3 + 0];
                const float w1 = proj_w[row * 3 + 1];
                const float w2 = proj_w[row * 3 + 2];
                const float va = (float)hA[i][e];
                const float vb = (float)hB[i][e];
                aO0 = fmaf(va, w0, aO0); aO1 = fmaf(va, w1, aO1); aO2 = fmaf(va, w2, aO2);
                bO0 = fmaf(vb, w0, bO0); bO1 = fmaf(vb, w1, bO1); bO2 = fmaf(vb, w2, bO2);
            }
        }
    }
    aO0 += __shfl_xor(aO0, 32, 64);
    aO1 += __shfl_xor(aO1, 32, 64);
    aO2 += __shfl_xor(aO2, 32, 64);
    bO0 += __shfl_xor(bO0, 32, 64);
    bO1 += __shfl_xor(bO1, 32, 64);
    bO2 += __shfl_xor(bO2, 32, 64);
    if (hh == 0) {
        if (gA < Bn) {
            out[3 * gA + 0] = aO0 + proj_b[0];
            out[3 * gA + 1] = aO1 + proj_b[1];
            out[3 * gA + 2] = aO2 + proj_b[2];
        }
        if (gB < Bn) {
            out[3 * gB + 0] = bO0 + proj_b[0];
            out[3 * gB + 1] = bO1 + proj_b[1];
            out[3 * gB + 2] = bO2 + proj_b[2];
        }
    }
}

extern "C" void kernel_launch(void* const* d_in, const int* in_sizes, int n_in,
                              void* d_out, int out_size, void* d_ws, size_t ws_size,
                              hipStream_t stream) {
    const float* x      = (const float*)d_in[0];
    const float* lift_w = (const float*)d_in[1];
    const float* lift_b = (const float*)d_in[2];
    const float* W1     = (const float*)d_in[3];
    const float* b1     = (const float*)d_in[4];
    const float* W2     = (const float*)d_in[5];
    const float* b2     = (const float*)d_in[6];
    const float* dts    = (const float*)d_in[7];
    const float* proj_w = (const float*)d_in[8];
    const float* proj_b = (const float*)d_in[9];
    float* out = (float*)d_out;

    const int B = in_sizes[0] / 3;
    half8* wf = (half8*)d_ws;   // NLAYERS*4*64*16 B = 200 KiB + 200 B dt table

    build_wfrags<<<NLAYERS, 64, 0, stream>>>(W1, b1, W2, b2, dts, wf);

    const int blocks = (B + 255) / 256;   // 256 samples/block (4 waves x 64)
    unet_mfma<<<blocks, 256, 0, stream>>>(
        x, lift_w, lift_b, proj_w, proj_b, wf, out, B);
}